// Round 1
// baseline (7300.356 us; speedup 1.0000x reference)
//
#include <hip/hip_runtime.h>

// bf16 types
typedef __bf16 bf16;
typedef bf16 bf16x8 __attribute__((ext_vector_type(8)));
typedef float f32x4 __attribute__((ext_vector_type(4)));

__device__ inline bf16x8 bzero8() {
  bf16x8 v;
#pragma unroll
  for (int i = 0; i < 8; ++i) v[i] = (bf16)0.f;
  return v;
}

// ---------------------------------------------------------------------------
// Implicit-GEMM conv, NHWC, 5x5 kernel.
//   A[m][k] = in[img(b)][y+ky-pad][x+kx-pad][c],  m=(b,y,x), k=((ky*5+kx)*CIN+c)
//   B[k][n] = wt[n][k]  (weights pre-transposed to [N][K] bf16)
// Tile 64x64, BK=32, 4 waves, v_mfma_f32_16x16x32_bf16.
// epi==0: out_bf[m*N+n] = bf16(acc + bias[n])          (xz buffer)
// epi==1: out_f[m*N+n]  = acc + xz[xzrow(m)*N+n]       (z = xz + conv(h))
// ---------------------------------------------------------------------------
template <int CIN, bool CONTIG>
__global__ void __launch_bounds__(256)
conv_gemm(const bf16* __restrict__ in, const bf16* __restrict__ wt,
          const float* __restrict__ bias, const bf16* __restrict__ xz,
          bf16* __restrict__ out_bf, float* __restrict__ out_f,
          int HoWo, int Wo, int inH, int inW, int pad,
          int img_mul, int img_add, int xz_mul, int xz_add,
          int N, int K, int epi)
{
  __shared__ bf16 As[64 * 40];   // stride 40 bf16 = 80B (16B-aligned, conflict-lite)
  __shared__ bf16 Bs[64 * 40];

  const int tid  = threadIdx.x;
  const int wave = tid >> 6;
  const int lane = tid & 63;
  const int m0 = blockIdx.x * 64;
  const int n0 = blockIdx.y * 64;

  // staging coords: 64 rows x 4 chunks of 8
  const int srow = tid >> 2;
  const int skq  = tid & 3;

  const int am  = m0 + srow;
  const int ab  = am / HoWo;
  const int apx = am - ab * HoWo;
  const int ay  = apx / Wo;
  const int ax  = apx - ay * Wo;
  const long inHW = (long)inH * inW;
  const bf16* inb  = in + (long)(ab * img_mul + img_add) * inHW * CIN;
  const bf16* wrow = wt + (long)(n0 + srow) * K;

  f32x4 acc[4];
#pragma unroll
  for (int r = 0; r < 4; ++r) { acc[r][0] = 0.f; acc[r][1] = 0.f; acc[r][2] = 0.f; acc[r][3] = 0.f; }

  const int lrow = lane & 15;
  const int lq   = lane >> 4;
  const int ksteps = (K + 31) >> 5;

  for (int ks = 0; ks < ksteps; ++ks) {
    const int k0 = ks << 5;
    const int k  = k0 + skq * 8;
    bf16x8 av, bv;
    if (CONTIG) {
      // CIN is 64/128: an 8-run never crosses a (ky,kx) boundary; K % 32 == 0
      const int c  = k % CIN;
      const int kc = k / CIN;
      const int ky = kc / 5;
      const int kx = kc - ky * 5;
      const int iy = ay + ky - pad;
      const int ix = ax + kx - pad;
      if ((unsigned)iy < (unsigned)inH && (unsigned)ix < (unsigned)inW)
        av = *(const bf16x8*)(inb + ((long)iy * inW + ix) * CIN + c);
      else
        av = bzero8();
      bv = *(const bf16x8*)(wrow + k);
    } else {
      // ragged K (layer-1 input conv: CIN=5, K=125): per-element with zero pad
#pragma unroll
      for (int j = 0; j < 8; ++j) {
        const int ke = k + j;
        bf16 v = (bf16)0.f, w = (bf16)0.f;
        if (ke < K) {
          const int c  = ke % CIN;
          const int kc = ke / CIN;
          const int ky = kc / 5;
          const int kx = kc - ky * 5;
          const int iy = ay + ky - pad;
          const int ix = ax + kx - pad;
          if ((unsigned)iy < (unsigned)inH && (unsigned)ix < (unsigned)inW)
            v = inb[((long)iy * inW + ix) * CIN + c];
          w = wrow[ke];
        }
        av[j] = v; bv[j] = w;
      }
    }
    *(bf16x8*)&As[srow * 40 + skq * 8] = av;
    *(bf16x8*)&Bs[srow * 40 + skq * 8] = bv;
    __syncthreads();

    bf16x8 bfrag = *(const bf16x8*)&Bs[(wave * 16 + lrow) * 40 + lq * 8];
#pragma unroll
    for (int r = 0; r < 4; ++r) {
      bf16x8 afrag = *(const bf16x8*)&As[(r * 16 + lrow) * 40 + lq * 8];
      acc[r] = __builtin_amdgcn_mfma_f32_16x16x32_bf16(afrag, bfrag, acc[r], 0, 0, 0);
    }
    __syncthreads();
  }

  // epilogue: C/D layout col=lane&15, row=(lane>>4)*4+reg  [m89-verified]
  const int col = n0 + wave * 16 + lrow;
  if (epi == 0) {
    const float bsv = bias[col];
#pragma unroll
    for (int r = 0; r < 4; ++r) {
#pragma unroll
      for (int q = 0; q < 4; ++q) {
        const int row = m0 + r * 16 + lq * 4 + q;
        out_bf[(long)row * N + col] = (bf16)(acc[r][q] + bsv);
      }
    }
  } else {
#pragma unroll
    for (int r = 0; r < 4; ++r) {
#pragma unroll
      for (int q = 0; q < 4; ++q) {
        const int row = m0 + r * 16 + lq * 4 + q;
        const int rb  = row / HoWo;
        const int rp  = row - rb * HoWo;
        const long xrow = (long)(rb * xz_mul + xz_add) * HoWo + rp;
        out_f[(long)row * N + col] = acc[r][q] + (float)xz[xrow * N + col];
      }
    }
  }
}

// ---------------------------------------------------------------------------
// Fused LSTM gates. z comes from hz (fp32, = xz + conv(h)) for t>0, else
// straight from xz (bf16, bias already included). keras gate order i,f,c,o.
// ---------------------------------------------------------------------------
__global__ void __launch_bounds__(256)
gate_kernel(const bf16* __restrict__ xz, const float* __restrict__ hz,
            float* __restrict__ c, bf16* __restrict__ hseq, float* __restrict__ hf,
            int HoWo, int F, int t, int T, int total)
{
  const int idx = blockIdx.x * 256 + threadIdx.x;
  if (idx >= total) return;
  const int f  = idx % F;
  const int bp = idx / F;            // b*HoWo + p
  const int b  = bp / HoWo;
  const int p  = bp - b * HoWo;
  const int N4 = 4 * F;

  float zi, zf, zc, zo;
  if (hz != nullptr) {
    const float* zp = hz + (long)bp * N4 + f;
    zi = zp[0]; zf = zp[F]; zc = zp[2 * F]; zo = zp[3 * F];
  } else {
    const bf16* zp = xz + ((long)(b * T + t) * HoWo + p) * N4 + f;
    zi = (float)zp[0]; zf = (float)zp[F]; zc = (float)zp[2 * F]; zo = (float)zp[3 * F];
  }
  const float cprev = (t > 0) ? c[idx] : 0.f;
  const float ig = fminf(fmaxf(0.2f * zi + 0.5f, 0.f), 1.f);
  const float fg = fminf(fmaxf(0.2f * zf + 0.5f, 0.f), 1.f);
  const float og = fminf(fmaxf(0.2f * zo + 0.5f, 0.f), 1.f);
  const float cn = fg * cprev + ig * tanhf(zc);
  const float h  = og * tanhf(cn);
  c[idx] = cn;
  hseq[((long)(b * T + t) * HoWo + p) * F + f] = (bf16)h;
  if (hf != nullptr) hf[idx] = h;
}

// ---------------------------------------------------------------------------
__global__ void __launch_bounds__(256)
cast_f32_bf16(const float* __restrict__ in, bf16* __restrict__ out, int n)
{
  const int i = blockIdx.x * 256 + threadIdx.x;
  if (i < n) out[i] = (bf16)in[i];
}

// weights (K,N) fp32 -> (N,K) bf16
__global__ void __launch_bounds__(256)
cast_transpose(const float* __restrict__ in, bf16* __restrict__ out, int K, int N)
{
  const int i = blockIdx.x * 256 + threadIdx.x;
  if (i < K * N) {
    const int k = i / N;
    const int n = i - k * N;
    out[(long)n * K + k] = (bf16)in[i];
  }
}

// ---------------------------------------------------------------------------
// split-K dense: out[b][j] += sum_{d in chunk} A[b][d] * W[d][j]   (atomic)
// thread = one j column (coalesced W reads), 16 batch accumulators.
// ---------------------------------------------------------------------------
__global__ void __launch_bounds__(256)
dense_splitk(const float* __restrict__ A, const float* __restrict__ W,
             float* __restrict__ out, int D, int N, int chunk)
{
  const int j  = blockIdx.x * 256 + threadIdx.x;
  const int d0 = blockIdx.y * chunk;
  int d1 = d0 + chunk; if (d1 > D) d1 = D;
  float acc[16];
#pragma unroll
  for (int b = 0; b < 16; ++b) acc[b] = 0.f;
  for (int d = d0; d < d1; ++d) {
    const float w = W[(long)d * N + j];
#pragma unroll
    for (int b = 0; b < 16; ++b) acc[b] += A[(long)b * D + d] * w;
  }
#pragma unroll
  for (int b = 0; b < 16; ++b) atomicAdd(&out[b * N + j], acc[b]);
}

__global__ void __launch_bounds__(256)
bias_relu(const float* __restrict__ in, const float* __restrict__ bias,
          float* __restrict__ out, int N, int total)
{
  const int i = blockIdx.x * 256 + threadIdx.x;
  if (i < total) {
    const int j = i % N;
    const float v = in[i] + bias[j];
    out[i] = v > 0.f ? v : 0.f;
  }
}

__global__ void __launch_bounds__(256)
dense3_kernel(const float* __restrict__ z, const float* __restrict__ W,
              const float* __restrict__ bias, float* __restrict__ out)
{
  const int b = blockIdx.x;     // 16
  const int tid = threadIdx.x;  // 256
  float a0 = 0.f, a1 = 0.f, a2 = 0.f, a3 = 0.f;
  for (int d = tid; d < 1024; d += 256) {
    const float zv = z[b * 1024 + d];
    a0 += zv * W[d * 4 + 0]; a1 += zv * W[d * 4 + 1];
    a2 += zv * W[d * 4 + 2]; a3 += zv * W[d * 4 + 3];
  }
  __shared__ float red[256][4];
  red[tid][0] = a0; red[tid][1] = a1; red[tid][2] = a2; red[tid][3] = a3;
  __syncthreads();
  for (int s = 128; s > 0; s >>= 1) {
    if (tid < s) {
      red[tid][0] += red[tid + s][0]; red[tid][1] += red[tid + s][1];
      red[tid][2] += red[tid + s][2]; red[tid][3] += red[tid + s][3];
    }
    __syncthreads();
  }
  if (tid < 4) out[b * 4 + tid] = red[0][tid] + bias[tid];
}

// ---------------------------------------------------------------------------
extern "C" void kernel_launch(void* const* d_in, const int* in_sizes, int n_in,
                              void* d_out, int out_size, void* d_ws, size_t ws_size,
                              hipStream_t stream)
{
  const float* x   = (const float*)d_in[0];
  const float* Wx1 = (const float*)d_in[1];
  const float* Wh1 = (const float*)d_in[2];
  const float* b1  = (const float*)d_in[3];
  const float* Wx2 = (const float*)d_in[4];
  const float* Wh2 = (const float*)d_in[5];
  const float* b2  = (const float*)d_in[6];
  const float* Wx3 = (const float*)d_in[7];
  const float* Wh3 = (const float*)d_in[8];
  const float* b3  = (const float*)d_in[9];
  const float* Wd1 = (const float*)d_in[10];
  const float* bd1 = (const float*)d_in[11];
  const float* Wd2 = (const float*)d_in[12];
  const float* bd2 = (const float*)d_in[13];
  const float* Wd3 = (const float*)d_in[14];
  const float* bd3 = (const float*)d_in[15];

  // workspace arena (~640 MB). xz1/xz2/xz3 share one region; h1seq|h2seq+h3seq share another.
  char* ws = (char*)d_ws;
  size_t off = 0;
  auto alloc = [&](size_t bytes) -> void* {
    void* p = ws + off;
    off += (bytes + 255) & ~(size_t)255;
    return p;
  };
  bf16* x_bf = (bf16*)alloc((size_t)1966080 * 2);
  bf16* wx1t = (bf16*)alloc((size_t)64000 * 2);     // [512][125]
  bf16* wh1t = (bf16*)alloc((size_t)1638400 * 2);   // [512][3200]
  bf16* wx2t = (bf16*)alloc((size_t)819200 * 2);    // [256][3200]
  bf16* wh2t = (bf16*)alloc((size_t)409600 * 2);    // [256][1600]
  bf16* wx3t = (bf16*)alloc((size_t)409600 * 2);    // [256][1600]
  bf16* wh3t = (bf16*)alloc((size_t)409600 * 2);    // [256][1600]
  bf16* xzA  = (bf16*)alloc((size_t)176947200 * 2); // xz1 (354MB) | xz2 | xz3
  bf16* hB   = (bf16*)alloc((size_t)44236800 * 2);  // h1seq (88.5MB) | h2seq+h3seq
  float* hzC = (float*)alloc((size_t)29491200 * 4); // hz1 (118MB) | hz2 | hz3
  float* c1  = (float*)alloc((size_t)7372800 * 4);
  float* c2  = (float*)alloc((size_t)3211264 * 4);
  float* c3  = (float*)alloc((size_t)2768896 * 4);
  float* h3f = (float*)alloc((size_t)2768896 * 4);
  float* out1 = (float*)alloc(16384 * 4);
  float* z1   = (float*)alloc(16384 * 4);
  float* out2 = (float*)alloc(16384 * 4);
  float* z2   = (float*)alloc(16384 * 4);
  bf16* h1seq = hB;
  bf16* h2seq = hB;                      // h1seq dead once xz2 is built
  bf16* h3seq = hB + (size_t)19267584;   // next to h2seq (byte offset 256-aligned)

  // ---- casts ----
  cast_f32_bf16<<<(1966080 + 255) / 256, 256, 0, stream>>>(x, x_bf, 1966080);
  cast_transpose<<<(64000 + 255) / 256, 256, 0, stream>>>(Wx1, wx1t, 125, 512);
  cast_transpose<<<(1638400 + 255) / 256, 256, 0, stream>>>(Wh1, wh1t, 3200, 512);
  cast_transpose<<<(819200 + 255) / 256, 256, 0, stream>>>(Wx2, wx2t, 3200, 256);
  cast_transpose<<<(409600 + 255) / 256, 256, 0, stream>>>(Wh2, wh2t, 1600, 256);
  cast_transpose<<<(409600 + 255) / 256, 256, 0, stream>>>(Wx3, wx3t, 1600, 256);
  cast_transpose<<<(409600 + 255) / 256, 256, 0, stream>>>(Wh3, wh3t, 1600, 256);

  // ---- layer 1: 64x64x5 -> 60x60x128, N=512 ----
  conv_gemm<5, false><<<dim3(5400, 8), 256, 0, stream>>>(
      x_bf, wx1t, b1, nullptr, xzA, nullptr,
      3600, 60, 64, 64, 0, 1, 0, 0, 0, 512, 125, 0);
  for (int t = 0; t < 6; ++t) {
    if (t > 0)
      conv_gemm<128, true><<<dim3(900, 8), 256, 0, stream>>>(
          h1seq, wh1t, nullptr, xzA, nullptr, hzC,
          3600, 60, 60, 60, 2, 6, t - 1, 6, t, 512, 3200, 1);
    gate_kernel<<<28800, 256, 0, stream>>>(xzA, (t > 0) ? hzC : nullptr,
                                           c1, h1seq, nullptr, 3600, 128, t, 6, 7372800);
  }

  // ---- layer 2: 60x60x128 -> 56x56x64, N=256 ----
  bf16* xz2 = xzA;
  conv_gemm<128, true><<<dim3(4704, 4), 256, 0, stream>>>(
      h1seq, wx2t, b2, nullptr, xz2, nullptr,
      3136, 56, 60, 60, 0, 1, 0, 0, 0, 256, 3200, 0);
  for (int t = 0; t < 6; ++t) {
    if (t > 0)
      conv_gemm<64, true><<<dim3(784, 4), 256, 0, stream>>>(
          h2seq, wh2t, nullptr, xz2, nullptr, hzC,
          3136, 56, 56, 56, 2, 6, t - 1, 6, t, 256, 1600, 1);
    gate_kernel<<<12544, 256, 0, stream>>>(xz2, (t > 0) ? hzC : nullptr,
                                           c2, h2seq, nullptr, 3136, 64, t, 6, 3211264);
  }

  // ---- layer 3: 56x56x64 -> 52x52x64, N=256, return last h ----
  bf16* xz3 = xzA;
  conv_gemm<64, true><<<dim3(4056, 4), 256, 0, stream>>>(
      h2seq, wx3t, b3, nullptr, xz3, nullptr,
      2704, 52, 56, 56, 0, 1, 0, 0, 0, 256, 1600, 0);
  for (int t = 0; t < 6; ++t) {
    if (t > 0)
      conv_gemm<64, true><<<dim3(676, 4), 256, 0, stream>>>(
          h3seq, wh3t, nullptr, xz3, nullptr, hzC,
          2704, 52, 52, 52, 2, 6, t - 1, 6, t, 256, 1600, 1);
    gate_kernel<<<10816, 256, 0, stream>>>(xz3, (t > 0) ? hzC : nullptr,
                                           c3, h3seq, h3f, 2704, 64, t, 6, 2768896);
  }

  // ---- dense head (fp32) ----
  hipMemsetAsync(out1, 0, 16384 * 4, stream);
  hipMemsetAsync(out2, 0, 16384 * 4, stream);
  dense_splitk<<<dim3(4, 169), 256, 0, stream>>>(h3f, Wd1, out1, 173056, 1024, 1024);
  bias_relu<<<64, 256, 0, stream>>>(out1, bd1, z1, 1024, 16384);
  dense_splitk<<<dim3(4, 4), 256, 0, stream>>>(z1, Wd2, out2, 1024, 1024, 256);
  bias_relu<<<64, 256, 0, stream>>>(out2, bd2, z2, 1024, 16384);
  dense3_kernel<<<16, 256, 0, stream>>>(z2, Wd3, bd3, (float*)d_out);
}

// Round 2
// 5446.549 us; speedup vs baseline: 1.3404x; 1.3404x over previous
//
#include <hip/hip_runtime.h>

// bf16 types
typedef __bf16 bf16;
typedef bf16 bf16x8 __attribute__((ext_vector_type(8)));
typedef float f32x4 __attribute__((ext_vector_type(4)));

__device__ inline bf16x8 bzero8() {
  bf16x8 v;
#pragma unroll
  for (int i = 0; i < 8; ++i) v[i] = (bf16)0.f;
  return v;
}

// async global->LDS, 16B per lane, dest = wave-uniform base + lane*16
__device__ __forceinline__ void gload_lds16(const bf16* g, bf16* l) {
  __builtin_amdgcn_global_load_lds(
      (const __attribute__((address_space(1))) void*)g,
      (__attribute__((address_space(3))) void*)l, 16, 0, 0);
}

// ---------------------------------------------------------------------------
// FAST implicit-GEMM conv (m93/m97 structure): 128x128 tile, BK=32, 4 waves
// in 2x2, each wave 4x4 MFMA tiles, global_load_lds width-16 staging.
// REQUIREMENTS (guaranteed by caller): M%128==0, N%128==0, K%32==0, and every
// A read in-bounds (recurrent convs read a zero-halo padded h buffer; VALID
// input convs are in-bounds by construction). CIN is a power of two.
//   A[m][k] = in[img][ay+ky][ax+kx][c], img=m/HoWo, k=((ky*5+kx)<<LOG2C)+c
//   B[k][n] = wt[n][k]  (weights pre-transposed to [N][K] bf16)
// epi==0: out_bf[m*N+n] = bf16(acc + bias[n])
// epi==1: out_f[m*N+n]  = acc + xz[((b*T+t)*HoWo+p)*N+n],  m = b*HoWo+p
// ---------------------------------------------------------------------------
template <int CIN, int LOG2C>
__global__ void __launch_bounds__(256)
conv_gemm128(const bf16* __restrict__ in, const bf16* __restrict__ wt,
             const float* __restrict__ bias, const bf16* __restrict__ xz,
             bf16* __restrict__ out_bf, float* __restrict__ out_f,
             int HoWo, int Wo, int inH, int inW,
             int T, int t, int N, int K, int epi)
{
  __shared__ bf16 As[128 * 32];   // stride 32 bf16 = 64B rows, DMA-contiguous
  __shared__ bf16 Bs[128 * 32];

  const int tid  = threadIdx.x;
  const int w    = tid >> 6;
  const int lane = tid & 63;
  const int n0 = blockIdx.x * 128;   // n fast axis: n-blocks of one m-tile adjacent
  const int m0 = blockIdx.y * 128;

  // staging: wave w, call j covers rows [j*64 + w*16, +16); lane -> (row,kq)
  const int srow = w * 16 + (lane >> 2);
  const int kq   = lane & 3;
  const long inHW = (long)inH * inW;

  long base_a[2];
#pragma unroll
  for (int j = 0; j < 2; ++j) {
    const int am  = m0 + srow + j * 64;
    const int img = am / HoWo;
    const int p   = am - img * HoWo;
    const int ay  = p / Wo;
    const int ax  = p - ay * Wo;
    base_a[j] = (img * inHW + (long)ay * inW + ax) << LOG2C;
  }
  const bf16* wrow0 = wt + (long)(n0 + srow) * K;
  const bf16* wrow1 = wt + (long)(n0 + srow + 64) * K;

  f32x4 acc[4][4];
#pragma unroll
  for (int r = 0; r < 4; ++r)
#pragma unroll
    for (int cq = 0; cq < 4; ++cq) {
      acc[r][cq][0] = 0.f; acc[r][cq][1] = 0.f;
      acc[r][cq][2] = 0.f; acc[r][cq][3] = 0.f;
    }

  const int lrow = lane & 15;
  const int lq   = lane >> 4;
  const int wm   = w & 1;
  const int wn   = w >> 1;
  bf16* AsW = As + w * 512;   // wave-uniform DMA dest bases
  bf16* BsW = Bs + w * 512;

#pragma unroll 4
  for (int k0 = 0; k0 < K; k0 += 32) {
    const int k  = k0 + kq * 8;
    const int c  = k & (CIN - 1);
    const int kc = k >> LOG2C;
    const int ky = kc / 5;
    const int kx = kc - ky * 5;
    const long off = ((long)(ky * inW + kx) << LOG2C) + c;
    gload_lds16(in + base_a[0] + off, AsW);
    gload_lds16(in + base_a[1] + off, AsW + 2048);
    gload_lds16(wrow0 + k, BsW);
    gload_lds16(wrow1 + k, BsW + 2048);
    __syncthreads();   // compiler drains vmcnt before s_barrier

    bf16x8 a_frag[4], b_frag[4];
#pragma unroll
    for (int r = 0; r < 4; ++r)
      a_frag[r] = *(const bf16x8*)&As[(wm * 64 + r * 16 + lrow) * 32 + lq * 8];
#pragma unroll
    for (int cq = 0; cq < 4; ++cq)
      b_frag[cq] = *(const bf16x8*)&Bs[(wn * 64 + cq * 16 + lrow) * 32 + lq * 8];
#pragma unroll
    for (int r = 0; r < 4; ++r)
#pragma unroll
      for (int cq = 0; cq < 4; ++cq)
        acc[r][cq] = __builtin_amdgcn_mfma_f32_16x16x32_bf16(a_frag[r], b_frag[cq],
                                                             acc[r][cq], 0, 0, 0);
    __syncthreads();
  }

  // epilogue: C/D layout col=lane&15, row=(lane>>4)*4+reg  [m89-verified]
  const int colb = n0 + wn * 64 + lrow;
  if (epi == 0) {
    float bsv[4];
#pragma unroll
    for (int cq = 0; cq < 4; ++cq) bsv[cq] = bias[colb + cq * 16];
#pragma unroll
    for (int r = 0; r < 4; ++r)
#pragma unroll
      for (int q = 0; q < 4; ++q) {
        const long row = m0 + wm * 64 + r * 16 + lq * 4 + q;
#pragma unroll
        for (int cq = 0; cq < 4; ++cq)
          out_bf[row * N + colb + cq * 16] = (bf16)(acc[r][cq][q] + bsv[cq]);
      }
  } else {
#pragma unroll
    for (int r = 0; r < 4; ++r)
#pragma unroll
      for (int q = 0; q < 4; ++q) {
        const int row = m0 + wm * 64 + r * 16 + lq * 4 + q;
        const int b   = row / HoWo;
        const int p   = row - b * HoWo;
        const long xrow = (long)(b * T + t) * HoWo + p;
#pragma unroll
        for (int cq = 0; cq < 4; ++cq) {
          const int nn = colb + cq * 16;
          out_f[(long)row * N + nn] = acc[r][cq][q] + (float)xz[xrow * N + nn];
        }
      }
  }
}

// ---------------------------------------------------------------------------
// Slow 64x64 path — kept ONLY for layer-1 input conv (CIN=5, ragged K=125).
// ---------------------------------------------------------------------------
template <int CIN>
__global__ void __launch_bounds__(256)
conv_gemm64(const bf16* __restrict__ in, const bf16* __restrict__ wt,
            const float* __restrict__ bias, bf16* __restrict__ out_bf,
            int HoWo, int Wo, int inH, int inW, int N, int K)
{
  __shared__ bf16 As[64 * 40];
  __shared__ bf16 Bs[64 * 40];

  const int tid  = threadIdx.x;
  const int wave = tid >> 6;
  const int lane = tid & 63;
  const int m0 = blockIdx.x * 64;
  const int n0 = blockIdx.y * 64;

  const int srow = tid >> 2;
  const int skq  = tid & 3;

  const int am  = m0 + srow;
  const int ab  = am / HoWo;
  const int apx = am - ab * HoWo;
  const int ay  = apx / Wo;
  const int ax  = apx - ay * Wo;
  const long inHW = (long)inH * inW;
  const bf16* inb  = in + (long)ab * inHW * CIN;
  const bf16* wrow = wt + (long)(n0 + srow) * K;

  f32x4 acc[4];
#pragma unroll
  for (int r = 0; r < 4; ++r) { acc[r][0] = 0.f; acc[r][1] = 0.f; acc[r][2] = 0.f; acc[r][3] = 0.f; }

  const int lrow = lane & 15;
  const int lq   = lane >> 4;
  const int ksteps = (K + 31) >> 5;

  for (int ks = 0; ks < ksteps; ++ks) {
    const int k = (ks << 5) + skq * 8;
    bf16x8 av = bzero8(), bv = bzero8();
#pragma unroll
    for (int j = 0; j < 8; ++j) {
      const int ke = k + j;
      if (ke < K) {
        const int c  = ke % CIN;
        const int kc = ke / CIN;
        const int ky = kc / 5;
        const int kx = kc - ky * 5;
        const int iy = ay + ky;
        const int ix = ax + kx;
        av[j] = inb[((long)iy * inW + ix) * CIN + c];
        bv[j] = wrow[ke];
      }
    }
    *(bf16x8*)&As[srow * 40 + skq * 8] = av;
    *(bf16x8*)&Bs[srow * 40 + skq * 8] = bv;
    __syncthreads();

    bf16x8 bfrag = *(const bf16x8*)&Bs[(wave * 16 + lrow) * 40 + lq * 8];
#pragma unroll
    for (int r = 0; r < 4; ++r) {
      bf16x8 afrag = *(const bf16x8*)&As[(r * 16 + lrow) * 40 + lq * 8];
      acc[r] = __builtin_amdgcn_mfma_f32_16x16x32_bf16(afrag, bfrag, acc[r], 0, 0, 0);
    }
    __syncthreads();
  }

  const int col = n0 + wave * 16 + lrow;
  const float bsv = bias[col];
#pragma unroll
  for (int r = 0; r < 4; ++r)
#pragma unroll
    for (int q = 0; q < 4; ++q) {
      const long row = m0 + r * 16 + lq * 4 + q;
      out_bf[row * N + col] = (bf16)(acc[r][q] + bsv);
    }
}

// ---------------------------------------------------------------------------
// Fused LSTM gates. Writes h to: hseq (next layer's input, optional),
// hpad (zero-halo padded buffer for next timestep's recurrent conv, optional),
// hf (fp32 final h for dense head, optional).
// ---------------------------------------------------------------------------
__global__ void __launch_bounds__(256)
gate_kernel(const bf16* __restrict__ xz, const float* __restrict__ hz,
            float* __restrict__ c, bf16* __restrict__ hseq,
            bf16* __restrict__ hpad, float* __restrict__ hf,
            int HoWo, int Wo, int Wp, int HpWp, int F, int t, int T, int total)
{
  const int idx = blockIdx.x * 256 + threadIdx.x;
  if (idx >= total) return;
  const int f  = idx % F;
  const int bp = idx / F;            // b*HoWo + p
  const int b  = bp / HoWo;
  const int p  = bp - b * HoWo;
  const int N4 = 4 * F;

  float zi, zf, zc, zo;
  if (hz != nullptr) {
    const float* zp = hz + (long)bp * N4 + f;
    zi = zp[0]; zf = zp[F]; zc = zp[2 * F]; zo = zp[3 * F];
  } else {
    const bf16* zp = xz + ((long)(b * T + t) * HoWo + p) * N4 + f;
    zi = (float)zp[0]; zf = (float)zp[F]; zc = (float)zp[2 * F]; zo = (float)zp[3 * F];
  }
  const float cprev = (t > 0) ? c[idx] : 0.f;
  const float ig = fminf(fmaxf(0.2f * zi + 0.5f, 0.f), 1.f);
  const float fg = fminf(fmaxf(0.2f * zf + 0.5f, 0.f), 1.f);
  const float og = fminf(fmaxf(0.2f * zo + 0.5f, 0.f), 1.f);
  const float cn = fg * cprev + ig * tanhf(zc);
  const float h  = og * tanhf(cn);
  c[idx] = cn;
  const bf16 hb = (bf16)h;
  if (hseq != nullptr)
    hseq[((long)(b * T + t) * HoWo + p) * F + f] = hb;
  if (hpad != nullptr) {
    const int y = p / Wo;
    const int x = p - y * Wo;
    hpad[((long)b * HpWp + (long)(y + 2) * Wp + (x + 2)) * F + f] = hb;
  }
  if (hf != nullptr) hf[idx] = h;
}

// ---------------------------------------------------------------------------
__global__ void __launch_bounds__(256)
cast_f32_bf16(const float* __restrict__ in, bf16* __restrict__ out, int n)
{
  const int i = blockIdx.x * 256 + threadIdx.x;
  if (i < n) out[i] = (bf16)in[i];
}

// weights (K,N) fp32 -> (N,K) bf16
__global__ void __launch_bounds__(256)
cast_transpose(const float* __restrict__ in, bf16* __restrict__ out, int K, int N)
{
  const int i = blockIdx.x * 256 + threadIdx.x;
  if (i < K * N) {
    const int k = i / N;
    const int n = i - k * N;
    out[(long)n * K + k] = (bf16)in[i];
  }
}

// ---------------------------------------------------------------------------
__global__ void __launch_bounds__(256)
dense_splitk(const float* __restrict__ A, const float* __restrict__ W,
             float* __restrict__ out, int D, int N, int chunk)
{
  const int j  = blockIdx.x * 256 + threadIdx.x;
  const int d0 = blockIdx.y * chunk;
  int d1 = d0 + chunk; if (d1 > D) d1 = D;
  float acc[16];
#pragma unroll
  for (int b = 0; b < 16; ++b) acc[b] = 0.f;
  for (int d = d0; d < d1; ++d) {
    const float w = W[(long)d * N + j];
#pragma unroll
    for (int b = 0; b < 16; ++b) acc[b] += A[(long)b * D + d] * w;
  }
#pragma unroll
  for (int b = 0; b < 16; ++b) atomicAdd(&out[b * N + j], acc[b]);
}

__global__ void __launch_bounds__(256)
bias_relu(const float* __restrict__ in, const float* __restrict__ bias,
          float* __restrict__ out, int N, int total)
{
  const int i = blockIdx.x * 256 + threadIdx.x;
  if (i < total) {
    const int j = i % N;
    const float v = in[i] + bias[j];
    out[i] = v > 0.f ? v : 0.f;
  }
}

__global__ void __launch_bounds__(256)
dense3_kernel(const float* __restrict__ z, const float* __restrict__ W,
              const float* __restrict__ bias, float* __restrict__ out)
{
  const int b = blockIdx.x;
  const int tid = threadIdx.x;
  float a0 = 0.f, a1 = 0.f, a2 = 0.f, a3 = 0.f;
  for (int d = tid; d < 1024; d += 256) {
    const float zv = z[b * 1024 + d];
    a0 += zv * W[d * 4 + 0]; a1 += zv * W[d * 4 + 1];
    a2 += zv * W[d * 4 + 2]; a3 += zv * W[d * 4 + 3];
  }
  __shared__ float red[256][4];
  red[tid][0] = a0; red[tid][1] = a1; red[tid][2] = a2; red[tid][3] = a3;
  __syncthreads();
  for (int s = 128; s > 0; s >>= 1) {
    if (tid < s) {
      red[tid][0] += red[tid + s][0]; red[tid][1] += red[tid + s][1];
      red[tid][2] += red[tid + s][2]; red[tid][3] += red[tid + s][3];
    }
    __syncthreads();
  }
  if (tid < 4) out[b * 4 + tid] = red[0][tid] + bias[tid];
}

// ---------------------------------------------------------------------------
extern "C" void kernel_launch(void* const* d_in, const int* in_sizes, int n_in,
                              void* d_out, int out_size, void* d_ws, size_t ws_size,
                              hipStream_t stream)
{
  const float* x   = (const float*)d_in[0];
  const float* Wx1 = (const float*)d_in[1];
  const float* Wh1 = (const float*)d_in[2];
  const float* b1  = (const float*)d_in[3];
  const float* Wx2 = (const float*)d_in[4];
  const float* Wh2 = (const float*)d_in[5];
  const float* b2  = (const float*)d_in[6];
  const float* Wx3 = (const float*)d_in[7];
  const float* Wh3 = (const float*)d_in[8];
  const float* b3  = (const float*)d_in[9];
  const float* Wd1 = (const float*)d_in[10];
  const float* bd1 = (const float*)d_in[11];
  const float* Wd2 = (const float*)d_in[12];
  const float* bd2 = (const float*)d_in[13];
  const float* Wd3 = (const float*)d_in[14];
  const float* bd3 = (const float*)d_in[15];

  char* ws = (char*)d_ws;
  size_t off = 0;
  auto alloc = [&](size_t bytes) -> void* {
    void* p = ws + off;
    off += (bytes + 255) & ~(size_t)255;
    return p;
  };
  bf16* x_bf = (bf16*)alloc((size_t)1966080 * 2);
  bf16* wx1t = (bf16*)alloc((size_t)64000 * 2);     // [512][125]
  bf16* wh1t = (bf16*)alloc((size_t)1638400 * 2);   // [512][3200]
  bf16* wx2t = (bf16*)alloc((size_t)819200 * 2);    // [256][3200]
  bf16* wh2t = (bf16*)alloc((size_t)409600 * 2);    // [256][1600]
  bf16* wx3t = (bf16*)alloc((size_t)409600 * 2);    // [256][1600]
  bf16* wh3t = (bf16*)alloc((size_t)409600 * 2);    // [256][1600]
  bf16* xzA  = (bf16*)alloc((size_t)176947200 * 2); // xz1 (354MB) | xz2 | xz3
  bf16* hB   = (bf16*)alloc((size_t)44236800 * 2);  // h1seq | h2seq
  float* hzC = (float*)alloc((size_t)29491200 * 4); // hz1 (118MB) | hz2 | hz3
  float* cA  = (float*)alloc((size_t)7372800 * 4);  // c1 | (c2,c3)
  float* h3f = (float*)alloc((size_t)2768896 * 4);
  bf16* hpadA = (bf16*)alloc((size_t)8388608 * 2);  // hpad1 | (hpad2,hpad3)
  float* out1 = (float*)alloc(16384 * 4);
  float* z1   = (float*)alloc(16384 * 4);
  float* out2 = (float*)alloc(16384 * 4);
  float* z2   = (float*)alloc(16384 * 4);

  bf16* h1seq = hB;
  bf16* h2seq = hB;                       // h1seq dead once xz2 built
  float* c1 = cA;
  float* c2 = cA;                         // c1 dead after layer 1
  float* c3 = cA + (size_t)3211264;
  bf16* hpad1 = hpadA;                    // [16][64][64][128]
  bf16* hpad2 = hpadA;                    // [16][60][60][64], after layer 1
  bf16* hpad3 = hpadA + (size_t)3686400;  // [16][56][56][64]

  // ---- weight/input casts ----
  cast_f32_bf16<<<(1966080 + 255) / 256, 256, 0, stream>>>(x, x_bf, 1966080);
  cast_transpose<<<(64000 + 255) / 256, 256, 0, stream>>>(Wx1, wx1t, 125, 512);
  cast_transpose<<<(1638400 + 255) / 256, 256, 0, stream>>>(Wh1, wh1t, 3200, 512);
  cast_transpose<<<(819200 + 255) / 256, 256, 0, stream>>>(Wx2, wx2t, 3200, 256);
  cast_transpose<<<(409600 + 255) / 256, 256, 0, stream>>>(Wh2, wh2t, 1600, 256);
  cast_transpose<<<(409600 + 255) / 256, 256, 0, stream>>>(Wx3, wx3t, 1600, 256);
  cast_transpose<<<(409600 + 255) / 256, 256, 0, stream>>>(Wh3, wh3t, 1600, 256);

  // ---- layer 1: 64x64x5 -> 60x60x128, N=512 ----
  hipMemsetAsync(hpadA, 0, (size_t)8388608 * 2, stream);  // zero halo (whole buf)
  conv_gemm64<5><<<dim3(5400, 8), 256, 0, stream>>>(
      x_bf, wx1t, b1, xzA, 3600, 60, 64, 64, 512, 125);
  for (int t = 0; t < 6; ++t) {
    if (t > 0)
      conv_gemm128<128, 7><<<dim3(4, 450), 256, 0, stream>>>(
          hpad1, wh1t, nullptr, xzA, nullptr, hzC,
          3600, 60, 64, 64, 6, t, 512, 3200, 1);
    gate_kernel<<<28800, 256, 0, stream>>>(
        xzA, (t > 0) ? hzC : nullptr, c1, h1seq,
        (t < 5) ? hpad1 : nullptr, nullptr,
        3600, 60, 64, 4096, 128, t, 6, 7372800);
  }

  // ---- layer 2: 60x60x128 -> 56x56x64, N=256 ----
  bf16* xz2 = xzA;
  conv_gemm128<128, 7><<<dim3(2, 2352), 256, 0, stream>>>(
      h1seq, wx2t, b2, nullptr, xz2, nullptr,
      3136, 56, 60, 60, 6, 0, 256, 3200, 0);
  hipMemsetAsync(hpad2, 0, (size_t)3686400 * 2, stream);
  for (int t = 0; t < 6; ++t) {
    if (t > 0)
      conv_gemm128<64, 6><<<dim3(2, 392), 256, 0, stream>>>(
          hpad2, wh2t, nullptr, xz2, nullptr, hzC,
          3136, 56, 60, 60, 6, t, 256, 1600, 1);
    gate_kernel<<<12544, 256, 0, stream>>>(
        xz2, (t > 0) ? hzC : nullptr, c2, h2seq,
        (t < 5) ? hpad2 : nullptr, nullptr,
        3136, 56, 60, 3600, 64, t, 6, 3211264);
  }

  // ---- layer 3: 56x56x64 -> 52x52x64, N=256, return last h only ----
  bf16* xz3 = xzA;
  conv_gemm128<64, 6><<<dim3(2, 2028), 256, 0, stream>>>(
      h2seq, wx3t, b3, nullptr, xz3, nullptr,
      2704, 52, 56, 56, 6, 0, 256, 1600, 0);
  hipMemsetAsync(hpad3, 0, (size_t)3211264 * 2, stream);
  for (int t = 0; t < 6; ++t) {
    if (t > 0)
      conv_gemm128<64, 6><<<dim3(2, 338), 256, 0, stream>>>(
          hpad3, wh3t, nullptr, xz3, nullptr, hzC,
          2704, 52, 56, 56, 6, t, 256, 1600, 1);
    gate_kernel<<<10816, 256, 0, stream>>>(
        xz3, (t > 0) ? hzC : nullptr, c3, nullptr,
        (t < 5) ? hpad3 : nullptr, (t == 5) ? h3f : nullptr,
        2704, 52, 56, 3136, 64, t, 6, 2768896);
  }

  // ---- dense head (fp32) ----
  hipMemsetAsync(out1, 0, 16384 * 4, stream);
  hipMemsetAsync(out2, 0, 16384 * 4, stream);
  dense_splitk<<<dim3(4, 169), 256, 0, stream>>>(h3f, Wd1, out1, 173056, 1024, 1024);
  bias_relu<<<64, 256, 0, stream>>>(out1, bd1, z1, 1024, 16384);
  dense_splitk<<<dim3(4, 4), 256, 0, stream>>>(z1, Wd2, out2, 1024, 1024, 256);
  bias_relu<<<64, 256, 0, stream>>>(out2, bd2, z2, 1024, 16384);
  dense3_kernel<<<16, 256, 0, stream>>>(z2, Wd3, bd3, (float*)d_out);
}